// Round 10
// baseline (696.873 us; speedup 1.0000x reference)
//
#include <hip/hip_runtime.h>
#include <hip/hip_bf16.h>
#include <math.h>

// Problem constants
#define BATCH 32
#define SEQ   1024
#define NS    4
#define DIM   192
#define ND    768
#define NH    3
#define HD    64
#define MLP   768
#define TOKENS (BATCH*SEQ)   // 32768

typedef __bf16 bf16;
typedef bf16  bf16x8 __attribute__((ext_vector_type(8)));
typedef bf16  bf16x4 __attribute__((ext_vector_type(4)));
typedef float f32x4  __attribute__((ext_vector_type(4)));

#define MFMA16(a,b,c) __builtin_amdgcn_mfma_f32_16x16x32_bf16(a,b,c,0,0,0)
#define LOG2E 1.44269504088896f

// raw v_exp_f32 (exp2) when available: OCML exp2f adds subnormal-handling VALU
// that we don't need (post-scale scores are in range; FTZ is harmless here).
#if defined(__has_builtin)
#if __has_builtin(__builtin_amdgcn_exp2f)
#define EXP2F(x) __builtin_amdgcn_exp2f(x)
#else
#define EXP2F(x) exp2f(x)
#endif
#else
#define EXP2F(x) exp2f(x)
#endif

// gelu via exact identity tanh(y) = 1 - 2/(1+exp2(2y*log2e)): replaces the
// OCML tanhf call (~20+ VALU) with ~5 ops on the raw-exp2 path.
// Overflow-safe: exp2->inf => t=1 => gelu=x; exp2->0 => t=-1 => gelu=0.
__device__ inline float gelu_tanh(float x) {
    float y = 0.7978845608028654f * (x + 0.044715f * x * x * x);
    float t = 1.0f - 2.0f / (1.0f + EXP2F(2.0f * LOG2E * y));
    return 0.5f * x * (1.0f + t);
}

// ---------------------------------------------------------------------------
// Weight prep -> FRAGMENT-LINEAR layout.
// For Bt[N][K]: element (n,k) -> ((ntile*KC + kch)*64 + quad*16 + nc)*8 + e
//   ntile=n/16, nc=n%16, kch=k/32, quad=(k%32)/8, e=k%8, KC=K/32.
// A wave's B-frag load is then `base + lane*8` = contiguous 1KB.
// z = 0..5: the six weights; z = 6: phiw (norm_w-scaled phi, 32xND).
// ---------------------------------------------------------------------------
__global__ __launch_bounds__(256) void wprep_kernel(
    const float* __restrict__ Wq, const float* __restrict__ Wk,
    const float* __restrict__ Wv, const float* __restrict__ Wo,
    const float* __restrict__ W1, const float* __restrict__ W2,
    const float* __restrict__ nw, const float* __restrict__ ppre,
    const float* __restrict__ ppost, const float* __restrict__ pres,
    bf16* __restrict__ wqkv, bf16* __restrict__ wot,
    bf16* __restrict__ w1t, bf16* __restrict__ w2t, bf16* __restrict__ phiw)
{
    const int z = blockIdx.z;
    const int tid = blockIdx.x * 256 + threadIdx.x;
    if (z == 6) {
        if (tid >= 32 * 96) return;          // N=32, K=768, KC=24
        const int n = tid / 96, k8 = tid % 96;
        const int kch = k8 >> 2, quad = k8 & 3;
        const int ntile = n >> 4, nc = n & 15;
        bf16* d = phiw + ((size_t)(ntile * 24 + kch) * 64 + quad * 16 + nc) * 8;
#pragma unroll
        for (int e = 0; e < 8; e++) {
            const int k = k8 * 8 + e;
            float v;
            if      (n < 4)  v = ppre [k * 4  + n];
            else if (n < 8)  v = ppost[k * 4  + n - 4];
            else if (n < 24) v = pres [k * 16 + n - 8];
            else             v = 0.f;
            d[e] = (bf16)(nw[k] * v);
        }
        return;
    }
    const float* src; bf16* dst; int K, N; float scale = 1.f;
    switch (z) {
        case 0: src = Wq; dst = wqkv;            K = 192; N = 192;
                scale = 0.125f * LOG2E; break;   // 1/sqrt(64)*log2e (exp2 softmax)
        case 1: src = Wk; dst = wqkv + 36864;    K = 192; N = 192; break;
        case 2: src = Wv; dst = wqkv + 73728;    K = 192; N = 192; break;
        case 3: src = Wo; dst = wot;             K = 192; N = 192; break;
        case 4: src = W1; dst = w1t;             K = 192; N = 768; break;
        default:src = W2; dst = w2t;             K = 768; N = 192; break;
    }
    const int K8 = K >> 3, KC = K >> 5;
    if (tid >= N * K8) return;
    const int n = tid / K8, k8 = tid % K8;
    const int kch = k8 >> 2, quad = k8 & 3;
    const int ntile = n >> 4, nc = n & 15;
    bf16* d = dst + ((size_t)(ntile * KC + kch) * 64 + quad * 16 + nc) * 8;
#pragma unroll
    for (int e = 0; e < 8; e++)
        d[e] = (bf16)(scale * src[(size_t)(k8 * 8 + e) * N + n]);
}

// ---------------------------------------------------------------------------
// prep: one wave per token. rinv[t] = rsqrt(mean(x^2)+eps); xb = bf16(x)
// ---------------------------------------------------------------------------
__global__ __launch_bounds__(64) void prep_kernel(
    const float* __restrict__ x, bf16* __restrict__ xb, float* __restrict__ rinv)
{
    const int tok = blockIdx.x, lane = threadIdx.x;
    const float* xt = x + (size_t)tok * ND;
    float4 xv[3];
    float ssq = 0.f;
#pragma unroll
    for (int r = 0; r < 3; r++) {
        xv[r] = ((const float4*)xt)[lane + 64 * r];
        ssq += xv[r].x*xv[r].x + xv[r].y*xv[r].y + xv[r].z*xv[r].z + xv[r].w*xv[r].w;
    }
#pragma unroll
    for (int off = 32; off; off >>= 1) ssq += __shfl_xor(ssq, off);
    if (lane == 0) rinv[tok] = rsqrtf(ssq / (float)ND + 1e-8f);
#pragma unroll
    for (int r = 0; r < 3; r++) {
        bf16x4 o = {(bf16)xv[r].x, (bf16)xv[r].y, (bf16)xv[r].z, (bf16)xv[r].w};
        *(bf16x4*)(xb + (size_t)tok * ND + 4 * (lane + 64 * r)) = o;
    }
}

// ---------------------------------------------------------------------------
// dots: MFMA GEMM  dots[t][n] = rinv[t] * (xb[t][:] . phi'[n][:])
// phiw frag-linear (KC=24, 2 n-tiles).
// ---------------------------------------------------------------------------
__global__ __launch_bounds__(256) void dots_kernel(
    const bf16* __restrict__ xb, const bf16* __restrict__ phiw,
    const float* __restrict__ rinv, float* __restrict__ dots)
{
    const int tid = threadIdx.x, lane = tid & 63, w = tid >> 6;
    const int quad = lane >> 4, c = lane & 15;
    const int tok0 = blockIdx.x * 64 + w * 16;

    f32x4 acc0 = {0.f,0.f,0.f,0.f}, acc1 = {0.f,0.f,0.f,0.f};
    const bf16* arow = xb + (size_t)(tok0 + c) * ND + quad * 8;
    const bf16* bbase = phiw + lane * 8;
#pragma unroll 6
    for (int k0 = 0; k0 < ND; k0 += 32) {
        const int kch = k0 >> 5;
        bf16x8 af  = *(const bf16x8*)(arow + k0);
        bf16x8 bf0 = *(const bf16x8*)(bbase + (size_t)kch * 512);
        bf16x8 bf1 = *(const bf16x8*)(bbase + (size_t)(24 + kch) * 512);
        acc0 = MFMA16(af, bf0, acc0);
        acc1 = MFMA16(af, bf1, acc1);
    }
#pragma unroll
    for (int r = 0; r < 4; r++) {
        const int tok = tok0 + quad * 4 + r;
        const float s = rinv[tok];
        dots[(size_t)tok * 32 + c]      = acc0[r] * s;
        dots[(size_t)tok * 32 + 16 + c] = acc1[r] * s;
    }
}

// ---------------------------------------------------------------------------
// sink: ONE LANE PER TOKEN. sigmoid gates + 20-iter 4x4 sinkhorn, all regs.
// hgate[t][20] = {hres[16], hpre[4]}; hpost[t][4].
// ---------------------------------------------------------------------------
__global__ __launch_bounds__(256) void sink_kernel(
    const float* __restrict__ dots, const float* __restrict__ b_pre,
    const float* __restrict__ b_post, const float* __restrict__ b_res,
    const float* __restrict__ a_pre, const float* __restrict__ a_post,
    const float* __restrict__ a_res,
    float* __restrict__ hgate, float* __restrict__ hpost)
{
    const int tok = blockIdx.x * 256 + threadIdx.x;
    const float* dt = dots + (size_t)tok * 32;
    float d[24];
#pragma unroll
    for (int i = 0; i < 6; i++) *(float4*)&d[i*4] = *(const float4*)(dt + i*4);

    const float apre = a_pre[0], apost = a_post[0], ares = a_res[0];
    float hpre[4], hpo[4], m[16];
#pragma unroll
    for (int i = 0; i < 4; i++) {
        hpre[i] = 1.f / (1.f + __expf(-(apre  * d[i]     + b_pre[i])));
        hpo[i]  = 2.f / (1.f + __expf(-(apost * d[4 + i] + b_post[i])));
    }
#pragma unroll
    for (int p = 0; p < 16; p++) m[p] = ares * d[8 + p] + b_res[p];

    float gm = m[0];
#pragma unroll
    for (int p = 1; p < 16; p++) gm = fmaxf(gm, m[p]);
#pragma unroll
    for (int p = 0; p < 16; p++) m[p] = __expf(m[p] - gm);

    for (int it = 0; it < 20; it++) {
#pragma unroll
        for (int i = 0; i < 4; i++) {
            const float inv = 1.f / (m[i*4+0] + m[i*4+1] + m[i*4+2] + m[i*4+3] + 1e-8f);
#pragma unroll
            for (int j = 0; j < 4; j++) m[i*4+j] *= inv;
        }
#pragma unroll
        for (int j = 0; j < 4; j++) {
            const float inv = 1.f / (m[0*4+j] + m[1*4+j] + m[2*4+j] + m[3*4+j] + 1e-8f);
#pragma unroll
            for (int i = 0; i < 4; i++) m[i*4+j] *= inv;
        }
    }

    float* hg = hgate + (size_t)tok * 20;
#pragma unroll
    for (int i = 0; i < 4; i++) *(float4*)(hg + i*4) = *(float4*)&m[i*4];
    *(float4*)(hg + 16) = *(float4*)hpre;
    *(float4*)(hpost + (size_t)tok * 4) = *(float4*)hpo;
}

// ---------------------------------------------------------------------------
// mix: one wave per token. xin = hpre . x streams; h1 = LN1(xin) bf16.
// (x_res is now produced by gemm_w2_final's epilogue.)
// ---------------------------------------------------------------------------
__global__ __launch_bounds__(64) void mix_kernel(
    const bf16* __restrict__ xb, const float* __restrict__ hgate,
    const float* __restrict__ ln1_w, const float* __restrict__ ln1_b,
    float* __restrict__ xin, bf16* __restrict__ h1)
{
    const int tok = blockIdx.x, lane = threadIdx.x;
    __shared__ float ldsx[ND];

    const bf16* xt = xb + (size_t)tok * ND;
#pragma unroll
    for (int r = 0; r < 3; r++) {
        const bf16x4 v = *(const bf16x4*)(xt + 4 * (lane + 64 * r));
        float4 f = {(float)v[0], (float)v[1], (float)v[2], (float)v[3]};
        ((float4*)ldsx)[lane + 64 * r] = f;
    }

    const float* hg = hgate + (size_t)tok * 20 + 16;
    float hpre[4];
#pragma unroll
    for (int i = 0; i < 4; i++) hpre[i] = hg[i];

    __syncthreads();

    float xi[3];
#pragma unroll
    for (int r = 0; r < 3; r++) {
        const int d = lane + 64 * r;
        xi[r] = hpre[0]*ldsx[d] + hpre[1]*ldsx[DIM+d]
              + hpre[2]*ldsx[2*DIM+d] + hpre[3]*ldsx[3*DIM+d];
    }
    float sum = xi[0] + xi[1] + xi[2];
#pragma unroll
    for (int off = 32; off; off >>= 1) sum += __shfl_xor(sum, off);
    const float mean = sum / (float)DIM;
    float vs = (xi[0]-mean)*(xi[0]-mean) + (xi[1]-mean)*(xi[1]-mean) + (xi[2]-mean)*(xi[2]-mean);
#pragma unroll
    for (int off = 32; off; off >>= 1) vs += __shfl_xor(vs, off);
    const float inv = rsqrtf(vs / (float)DIM + 1e-5f);

    float* xint = xin + (size_t)tok * DIM;
    bf16*  ht   = h1  + (size_t)tok * DIM;
#pragma unroll
    for (int r = 0; r < 3; r++) {
        const int d = lane + 64 * r;
        xint[d] = xi[r];
        ht[d]   = (bf16)((xi[r] - mean) * inv * ln1_w[d] + ln1_b[d]);
    }
}

// ---------------------------------------------------------------------------
// Barrier-free bf16 GEMM, frag-linear B. Wave tile 64 tok x 64 n.
// EPI: 0 = bf16 out, 2 = gelu bf16 out
// ---------------------------------------------------------------------------
template<int EPI, int K>
__global__ __launch_bounds__(256) void gemm_bf(
    const bf16* __restrict__ A, const bf16* __restrict__ Bt,
    bf16* __restrict__ Cb, int N)
{
    const int tid = threadIdx.x, lane = tid & 63, w = tid >> 6;
    const int quad = lane >> 4, c = lane & 15;
    const int tok0 = blockIdx.y * 256 + w * 64;
    const int n0   = blockIdx.x * 64;
    const int KC   = K >> 5;

    f32x4 acc[4][4];
#pragma unroll
    for (int i = 0; i < 4; i++)
#pragma unroll
        for (int j = 0; j < 4; j++) acc[i][j] = (f32x4){0.f,0.f,0.f,0.f};

    const bf16* abase = A + (size_t)(tok0 + c) * K + quad * 8;
    const bf16* bbase = Bt + (size_t)(n0 >> 4) * KC * 512 + lane * 8;
#pragma unroll 2
    for (int k0 = 0; k0 < K; k0 += 32) {
        const int kch = k0 >> 5;
        bf16x8 af[4], bfr[4];
#pragma unroll
        for (int mt = 0; mt < 4; mt++)
            af[mt] = *(const bf16x8*)(abase + (size_t)mt * 16 * K + k0);
#pragma unroll
        for (int nt = 0; nt < 4; nt++)
            bfr[nt] = *(const bf16x8*)(bbase + (size_t)(nt * KC + kch) * 512);
#pragma unroll
        for (int mt = 0; mt < 4; mt++)
#pragma unroll
            for (int nt = 0; nt < 4; nt++)
                acc[mt][nt] = MFMA16(af[mt], bfr[nt], acc[mt][nt]);
    }

#pragma unroll
    for (int mt = 0; mt < 4; mt++)
#pragma unroll
        for (int r = 0; r < 4; r++) {
            const int row = tok0 + mt*16 + quad*4 + r;
#pragma unroll
            for (int nt = 0; nt < 4; nt++) {
                float v = acc[mt][nt][r];
                if (EPI == 2) v = gelu_tanh(v);
                Cb[(size_t)row * N + n0 + nt*16 + c] = (bf16)v;
            }
        }
}

// ---------------------------------------------------------------------------
// Wo GEMM + residual + LN2 fused. Wave = 16 tokens x 192 cols (nt=12).
// x1 = xin + obuf@Wo (fp32);  h2 = LN2(x1) (bf16). Frag-linear B, KC=6.
// ---------------------------------------------------------------------------
__global__ __launch_bounds__(256) void gemm_wo_ln(
    const bf16* __restrict__ A, const bf16* __restrict__ Bt,
    const float* __restrict__ xin, const float* __restrict__ lw,
    const float* __restrict__ lb, float* __restrict__ x1, bf16* __restrict__ h2)
{
    const int tid = threadIdx.x, lane = tid & 63, w = tid >> 6;
    const int quad = lane >> 4, c = lane & 15;
    const int tok0 = blockIdx.x * 64 + w * 16;

    f32x4 acc[12];
#pragma unroll
    for (int j = 0; j < 12; j++) acc[j] = (f32x4){0.f,0.f,0.f,0.f};

    const bf16* abase = A + (size_t)(tok0 + c) * 192 + quad * 8;
    const bf16* bbase = Bt + lane * 8;
#pragma unroll 2
    for (int k0 = 0; k0 < 192; k0 += 32) {
        const int kch = k0 >> 5;
        bf16x8 af = *(const bf16x8*)(abase + k0);
#pragma unroll
        for (int nt = 0; nt < 12; nt++) {
            bf16x8 bfr = *(const bf16x8*)(bbase + (size_t)(nt * 6 + kch) * 512);
            acc[nt] = MFMA16(af, bfr, acc[nt]);
        }
    }

#pragma unroll
    for (int r = 0; r < 4; r++) {
        const int row = tok0 + quad*4 + r;
        float v[12], s = 0.f;
#pragma unroll
        for (int nt = 0; nt < 12; nt++) {
            v[nt] = acc[nt][r] + xin[(size_t)row * 192 + nt*16 + c];
            s += v[nt];
        }
#pragma unroll
        for (int off = 1; off < 16; off <<= 1) s += __shfl_xor(s, off);
        const float mean = s / 192.f;
        float vv = 0.f;
#pragma unroll
        for (int nt = 0; nt < 12; nt++) {
            const float d = v[nt] - mean;
            vv += d * d;
        }
#pragma unroll
        for (int off = 1; off < 16; off <<= 1) vv += __shfl_xor(vv, off);
        const float inv = rsqrtf(vv / 192.f + 1e-5f);
#pragma unroll
        for (int nt = 0; nt < 12; nt++) {
            const int col = nt*16 + c;
            x1[(size_t)row * 192 + col] = v[nt];
            h2[(size_t)row * 192 + col] = (bf16)((v[nt] - mean) * inv * lw[col] + lb[col]);
        }
    }
}

// ---------------------------------------------------------------------------
// W2 GEMM + residual + h_post scale + x_res, fully fused; out is WRITE-ONLY.
// v3: gemm_bf's proven 64-tok x 64-col wave tile (mt=4): FOUR independent
// A-loads feed 16 MFMAs per K-step -> 4-deep natural load pipelining.
// Grid (3, TOKENS/256); A re-read 3x (cheap: L3-resident).
// out[t][i][col] = sum_j hres[i][j]*x[t][j][col] + (x1+g@W2)[t][col]*hpost[t][i]
// ---------------------------------------------------------------------------
__global__ __launch_bounds__(256) void gemm_w2_final(
    const bf16* __restrict__ A, const bf16* __restrict__ Bt,
    const float* __restrict__ x1, const float* __restrict__ x,
    const float* __restrict__ hgate, const float* __restrict__ hpost,
    float* __restrict__ out)
{
    const int tid = threadIdx.x, lane = tid & 63, w = tid >> 6;
    const int quad = lane >> 4, c = lane & 15;
    const int tok0 = blockIdx.y * 256 + w * 64;
    const int n0   = blockIdx.x * 64;

    f32x4 acc[4][4];
#pragma unroll
    for (int i = 0; i < 4; i++)
#pragma unroll
        for (int j = 0; j < 4; j++) acc[i][j] = (f32x4){0.f,0.f,0.f,0.f};

    const bf16* abase = A + (size_t)(tok0 + c) * 768 + quad * 8;
    const bf16* bbase = Bt + (size_t)(n0 >> 4) * 24 * 512 + lane * 8;
#pragma unroll 2
    for (int k0 = 0; k0 < 768; k0 += 32) {
        const int kch = k0 >> 5;
        bf16x8 af[4], bfr[4];
#pragma unroll
        for (int mt = 0; mt < 4; mt++)
            af[mt] = *(const bf16x8*)(abase + (size_t)mt * 16 * 768 + k0);
#pragma unroll
        for (int nt = 0; nt < 4; nt++)
            bfr[nt] = *(const bf16x8*)(bbase + (size_t)(nt * 24 + kch) * 512);
#pragma unroll
        for (int mt = 0; mt < 4; mt++)
#pragma unroll
            for (int nt = 0; nt < 4; nt++)
                acc[mt][nt] = MFMA16(af[mt], bfr[nt], acc[mt][nt]);
    }

#pragma unroll
    for (int mt = 0; mt < 4; mt++)
#pragma unroll
        for (int r = 0; r < 4; r++) {
            const int row = tok0 + mt*16 + quad*4 + r;
            const float* hg = hgate + (size_t)row * 20;
            float hres[16];
#pragma unroll
            for (int p = 0; p < 16; p++) hres[p] = hg[p];
            const float4 hp = *(const float4*)(hpost + (size_t)row * 4);
            const float hpi[4] = {hp.x, hp.y, hp.z, hp.w};
            const float* xrow = x + (size_t)row * ND;
            float* orow = out + (size_t)row * ND;
#pragma unroll
            for (int nt = 0; nt < 4; nt++) {
                const int col = n0 + nt*16 + c;
                const float y = acc[mt][nt][r] + x1[(size_t)row * 192 + col];
                float xv[4];
#pragma unroll
                for (int j = 0; j < 4; j++) xv[j] = xrow[j * 192 + col];
#pragma unroll
                for (int i = 0; i < 4; i++) {
                    const float xr = hres[i*4+0]*xv[0] + hres[i*4+1]*xv[1]
                                   + hres[i*4+2]*xv[2] + hres[i*4+3]*xv[3];
                    orow[i * 192 + col] = xr + y * hpi[i];
                }
            }
        }
}

// ---------------------------------------------------------------------------
// V transpose: qkv[tok][384+h*64+d] -> vt[bh][d][seq]  (bf16)
// ---------------------------------------------------------------------------
__global__ __launch_bounds__(256) void vtrans_kernel(
    const bf16* __restrict__ qkv, bf16* __restrict__ vt)
{
    __shared__ bf16 t[64][72];
    const int tid = threadIdx.x;
    const int bh = blockIdx.y, b = bh / NH, h = bh % NH;
    const int s0 = blockIdx.x * 64;

#pragma unroll
    for (int i = 0; i < 2; i++) {
        const int chunk = tid + 256 * i;
        const int srow = chunk >> 3, g = chunk & 7;
        *(uint4*)&t[srow][g * 8] =
            *(const uint4*)(qkv + (size_t)(b * SEQ + s0 + srow) * 576 + 384 + h * 64 + g * 8);
    }
    __syncthreads();
#pragma unroll
    for (int i = 0; i < 2; i++) {
        const int chunk = tid + 256 * i;
        const int d = chunk >> 3, sg = chunk & 7;
        bf16x8 v;
#pragma unroll
        for (int j = 0; j < 8; j++) v[j] = t[sg * 8 + j][d];
        *(bf16x8*)(vt + ((size_t)bh * HD + d) * SEQ + s0 + sg * 8) = v;
    }
}

// ---------------------------------------------------------------------------
// attn tile body: V(kt) issued at top (covered by QK+exp+Pw ~600cy),
// K(kt+1) prefetched into knxt (covered by the whole iteration).
// Static A/B buffer indexing (no runtime-indexed arrays -> no scratch).
// ---------------------------------------------------------------------------
__device__ __forceinline__ void attn_tile_body(
    int kt, bool pref,
    const bf16* __restrict__ kbase, const bf16* __restrict__ vbase,
    bf16* __restrict__ Pw, int quad, int c,
    const bf16x8 (&qf)[2][2],
    const bf16x8 (&kcur)[2][4], bf16x8 (&knxt)[2][4],
    f32x4 (&of)[2][4], float (&lst)[2][4])
{
    // V(kt): issue early, consumed by PV at the bottom
    bf16x8 vf[2][4];
#pragma unroll
    for (int ch = 0; ch < 2; ch++)
#pragma unroll
        for (int dt = 0; dt < 4; dt++)
            vf[ch][dt] = *(const bf16x8*)(vbase + (size_t)(dt*16 + c) * SEQ
                                          + kt*64 + ch*32 + quad*8);
    // K(kt+1): prefetch, consumed next tile
    if (pref) {
#pragma unroll
        for (int ch = 0; ch < 2; ch++)
#pragma unroll
            for (int nt = 0; nt < 4; nt++)
                knxt[ch][nt] = *(const bf16x8*)(kbase
                    + (size_t)((kt+1)*64 + nt*16 + c) * 576 + ch*32 + quad*8);
    }

    f32x4 sf[2][4];
#pragma unroll
    for (int mt = 0; mt < 2; mt++)
#pragma unroll
        for (int nt = 0; nt < 4; nt++) sf[mt][nt] = (f32x4){0.f, 0.f, 0.f, 0.f};
#pragma unroll
    for (int ch = 0; ch < 2; ch++)
#pragma unroll
        for (int mt = 0; mt < 2; mt++)
#pragma unroll
            for (int nt = 0; nt < 4; nt++)
                sf[mt][nt] = MFMA16(qf[mt][ch], kcur[ch][nt], sf[mt][nt]);

#pragma unroll
    for (int mt = 0; mt < 2; mt++)
#pragma unroll
        for (int r = 0; r < 4; r++) {
            float rs = 0.f;
#pragma unroll
            for (int nt = 0; nt < 4; nt++) {
                const float p = EXP2F(sf[mt][nt][r]);
                sf[mt][nt][r] = p;
                rs += p;
            }
            lst[mt][r] += rs;
        }

#pragma unroll
    for (int mt = 0; mt < 2; mt++)
#pragma unroll
        for (int nt = 0; nt < 4; nt++)
#pragma unroll
            for (int r = 0; r < 4; r++) {
                const int row = mt*16 + quad*4 + r;
                const int col = nt*16 + c;
                Pw[row*64 + (((col >> 3) ^ (row & 7)) * 8) + (col & 7)] =
                    (bf16)sf[mt][nt][r];
            }

#pragma unroll
    for (int ch = 0; ch < 2; ch++) {
        bf16x8 pf[2];
#pragma unroll
        for (int mt = 0; mt < 2; mt++) {
            const int row = mt*16 + c;
            pf[mt] = *(const bf16x8*)(Pw + row*64 + (((ch*4 + quad) ^ (c & 7)) * 8));
        }
#pragma unroll
        for (int mt = 0; mt < 2; mt++)
#pragma unroll
            for (int dt = 0; dt < 4; dt++)
                of[mt][dt] = MFMA16(pf[mt], vf[ch][dt], of[mt][dt]);
    }
}

// ---------------------------------------------------------------------------
// MFMA flash attention v7: R8's proven pipelined body (K-register prefetch +
// early V issue, 99.7us @ VGPR 136 / 3 waves/SIMD) with a 128-VGPR cap via
// __launch_bounds__(64, 4) to recover the 4-waves/SIMD residency tier
// (v0 evidence: 120 VGPR -> 16.6% occ vs R8's 136 -> 10.7%). The allocator
// must shave only 8 regs -- rematerialization, not memory spills (R2's
// catastrophic squeeze was 120->64). Tripwire: FETCH/WRITE inflation.
// exp2 softmax (log2e/8 folded into Wq), row-sum deferred to epilogue.
// ---------------------------------------------------------------------------
__global__ __launch_bounds__(64, 4) void attn_mfma(
    const bf16* __restrict__ qkv, const bf16* __restrict__ vt,
    bf16* __restrict__ obuf)
{
    __shared__ bf16 Pw[32 * 64];
    const int lane = threadIdx.x;
    const int quad = lane >> 4, c = lane & 15;
    const int bh = blockIdx.y, b = bh / NH, h = bh % NH;
    const int q0 = blockIdx.x * 32;

    const bf16* kbase = qkv + (size_t)b * SEQ * 576 + 192 + h * 64;
    const bf16* vbase = vt + (size_t)bh * HD * SEQ;

    bf16x8 qf[2][2];
#pragma unroll
    for (int mt = 0; mt < 2; mt++)
#pragma unroll
        for (int ch = 0; ch < 2; ch++)
            qf[mt][ch] = *(const bf16x8*)(qkv + (size_t)(b * SEQ + q0 + mt*16 + c) * 576
                                              + h * 64 + ch * 32 + quad * 8);

    f32x4 of[2][4];
    float lst[2][4];
#pragma unroll
    for (int mt = 0; mt < 2; mt++)
#pragma unroll
        for (int r = 0; r < 4; r++) lst[mt][r] = 0.f;
#pragma unroll
    for (int mt = 0; mt < 2; mt++)
#pragma unroll
        for (int dt = 0; dt < 4; dt++) of[mt][dt] = (f32x4){0.f, 0.f, 0.f, 0.f};

    // preload K tile 0 into buffer A
    bf16x8 kfA[2][4], kfB[2][4];
#pragma unroll
    for (int ch = 0; ch < 2; ch++)
#pragma unroll
        for (int nt = 0; nt < 4; nt++)
            kfA[ch][nt] = *(const bf16x8*)(kbase + (size_t)(nt*16 + c) * 576
                                           + ch * 32 + quad * 8);

#pragma unroll 1
    for (int kt2 = 0; kt2 < SEQ / 64; kt2 += 2) {
        attn_tile_body(kt2,     true,           kbase, vbase, Pw, quad, c,
                       qf, kfA, kfB, of, lst);
        attn_tile_body(kt2 + 1, kt2 + 2 < SEQ/64, kbase, vbase, Pw, quad, c,
                       qf, kfB, kfA, of, lst);
    }

#pragma unroll
    for (int mt = 0; mt < 2; mt++)
#pragma unroll
        for (int r = 0; r < 4; r++) {
            float s = lst[mt][r];
#pragma unroll
            for (int off = 1; off < 16; off <<= 1) s += __shfl_xor(s, off);
            const float inv = 1.0f / s;
            const size_t tok = (size_t)b * SEQ + q0 + mt*16 + quad*4 + r;
#pragma unroll
            for (int dt = 0; dt < 4; dt++)
                obuf[tok * DIM + h*64 + dt*16 + c] = (bf16)(of[mt][dt][r] * inv);
        }
}

// ---------------------------------------------------------------------------
extern "C" void kernel_launch(void* const* d_in, const int* in_sizes, int n_in,
                              void* d_out, int out_size, void* d_ws, size_t ws_size,
                              hipStream_t stream) {
    const float* x         = (const float*)d_in[0];
    const float* norm_w    = (const float*)d_in[1];
    const float* phi_pre   = (const float*)d_in[2];
    const float* phi_post  = (const float*)d_in[3];
    const float* phi_res   = (const float*)d_in[4];
    const float* b_pre     = (const float*)d_in[5];
    const float* b_post    = (const float*)d_in[6];
    const float* b_res     = (const float*)d_in[7];
    const float* alpha_pre = (const float*)d_in[8];
    const float* alpha_post= (const float*)d_in[9];
    const float* alpha_res = (const float*)d_in[10];
    const float* ln1_w     = (const float*)d_in[11];
    const float* ln1_b     = (const float*)d_in[12];
    const float* Wq        = (const float*)d_in[13];
    const float* Wk        = (const float*)d_in[14];
    const float* Wv        = (const float*)d_in[15];
    const float* Wo        = (const float*)d_in[16];
    const float* ln2_w     = (const float*)d_in[17];
    const float* ln2_b     = (const float*)d_in[18];
    const float* W1        = (const float*)d_in[19];
    const float* W2        = (const float*)d_in[20];

    float* out = (float*)d_out;
    float* ws  = (float*)d_ws;

    // ---- workspace carve (float units) — total ~130 MB ----
    const size_t TBf = (size_t)TOKENS * DIM;         // 6,291,456
    float* xin   = ws;                                // fp32 [TBf]
    float* x1    = ws + TBf;                          // fp32 [TBf]
    float* hpost = ws + 2 * TBf;                      // fp32 [131072]
    float* rinv  = hpost + 131072;                    // fp32 [32768]
    float* hgate = rinv + 32768;                      // fp32 [TOKENS*20] (alive to end!)
    bf16*  phiw  = (bf16*)(hgate + (size_t)TOKENS*20);// frag-linear [24576]
    bf16*  wqkv  = phiw + 24576;                      // [110592]
    bf16*  wot   = wqkv + 110592;                     // [36864]
    bf16*  w1t   = wot + 36864;                       // [147456]
    bf16*  w2t   = w1t + 147456;                      // [147456]
    float* regAC = (float*)(w2t + 147456);            // 12,582,912 floats
    bf16*  xb    = (bf16*)regAC;                      // [32768][768] (dead after mix)
    bf16*  qkv   = (bf16*)regAC;                      // [32768][576]
    bf16*  vt    = qkv + (size_t)TOKENS * 576;        // [96][64][1024]
    bf16*  gbuf  = (bf16*)regAC;                      // [32768][768] (after attn)
    float* regBD = regAC + 12582912;
    bf16*  h1    = (bf16*)regBD;                      // [32768][192]
    bf16*  obuf  = h1;                                // alias (h1 dead after QKV)
    bf16*  h2    = h1 + TBf;                          // [32768][192]
    float* dotsb = regBD + TBf / 2;                   // aliases h2 slot (dead before wo_ln)

    // 0. weight prep (frag-linear; 1/sqrt(64)*log2e folded into Wq)
    wprep_kernel<<<dim3(72, 1, 7), 256, 0, stream>>>(
        Wq, Wk, Wv, Wo, W1, W2, norm_w, phi_pre, phi_post, phi_res,
        wqkv, wot, w1t, w2t, phiw);

    // 1. gating pipeline
    prep_kernel<<<TOKENS, 64, 0, stream>>>(x, xb, rinv);
    dots_kernel<<<TOKENS / 64, 256, 0, stream>>>(xb, phiw, rinv, dotsb);
    sink_kernel<<<TOKENS / 256, 256, 0, stream>>>(
        dotsb, b_pre, b_post, b_res, alpha_pre, alpha_post, alpha_res, hgate, hpost);
    mix_kernel<<<TOKENS, 64, 0, stream>>>(xb, hgate, ln1_w, ln1_b, xin, h1);

    // 2. fused QKV projection (barrier-free, frag-linear B)
    gemm_bf<0, 192><<<dim3(576/64, TOKENS/256), 256, 0, stream>>>(h1, wqkv, qkv, 576);

    // 3. V transpose
    vtrans_kernel<<<dim3(SEQ/64, BATCH*NH), 256, 0, stream>>>(qkv, vt);

    // 4. attention -> obuf bf16 (1-wave blocks, K-prefetch, 128-VGPR cap)
    attn_mfma<<<dim3(SEQ/32, BATCH*NH), 64, 0, stream>>>(qkv, vt, obuf);

    // 5. x1 = xin + obuf @ Wo, h2 = LN2(x1)  (fused)
    gemm_wo_ln<<<TOKENS/64, 256, 0, stream>>>(obuf, wot, xin, ln2_w, ln2_b, x1, h2);

    // 6. g = gelu(h2 @ W1) bf16 (barrier-free, fast-gelu epilogue)
    gemm_bf<2, 192><<<dim3(768/64, TOKENS/256), 256, 0, stream>>>(h2, w1t, gbuf, 768);

    // 7. out = x_res + (x1 + g @ W2) * h_post  (fused; 64x64 wave tile, mt=4)
    gemm_w2_final<<<dim3(3, TOKENS/256), 256, 0, stream>>>(
        gbuf, w2t, x1, x, hgate, hpost, out);
}

// Round 11
// 522.023 us; speedup vs baseline: 1.3349x; 1.3349x over previous
//
#include <hip/hip_runtime.h>
#include <hip/hip_bf16.h>
#include <math.h>

// Problem constants
#define BATCH 32
#define SEQ   1024
#define NS    4
#define DIM   192
#define ND    768
#define NH    3
#define HD    64
#define MLP   768
#define TOKENS (BATCH*SEQ)   // 32768

typedef __bf16 bf16;
typedef bf16  bf16x8 __attribute__((ext_vector_type(8)));
typedef bf16  bf16x4 __attribute__((ext_vector_type(4)));
typedef float f32x4  __attribute__((ext_vector_type(4)));

#define MFMA16(a,b,c) __builtin_amdgcn_mfma_f32_16x16x32_bf16(a,b,c,0,0,0)
#define LOG2E 1.44269504088896f

// raw v_exp_f32 (exp2) when available: OCML exp2f adds subnormal-handling VALU
// that we don't need (post-scale scores are in range; FTZ is harmless here).
#if defined(__has_builtin)
#if __has_builtin(__builtin_amdgcn_exp2f)
#define EXP2F(x) __builtin_amdgcn_exp2f(x)
#else
#define EXP2F(x) exp2f(x)
#endif
#else
#define EXP2F(x) exp2f(x)
#endif

// gelu via exact identity tanh(y) = 1 - 2/(1+exp2(2y*log2e)): replaces the
// OCML tanhf call (~20+ VALU) with ~5 ops on the raw-exp2 path.
// Overflow-safe: exp2->inf => t=1 => gelu=x; exp2->0 => t=-1 => gelu=0.
__device__ inline float gelu_tanh(float x) {
    float y = 0.7978845608028654f * (x + 0.044715f * x * x * x);
    float t = 1.0f - 2.0f / (1.0f + EXP2F(2.0f * LOG2E * y));
    return 0.5f * x * (1.0f + t);
}

// ---------------------------------------------------------------------------
// Weight prep -> FRAGMENT-LINEAR layout.
// For Bt[N][K]: element (n,k) -> ((ntile*KC + kch)*64 + quad*16 + nc)*8 + e
//   ntile=n/16, nc=n%16, kch=k/32, quad=(k%32)/8, e=k%8, KC=K/32.
// A wave's B-frag load is then `base + lane*8` = contiguous 1KB.
// z = 0..5: the six weights; z = 6: phiw (norm_w-scaled phi, 32xND).
// ---------------------------------------------------------------------------
__global__ __launch_bounds__(256) void wprep_kernel(
    const float* __restrict__ Wq, const float* __restrict__ Wk,
    const float* __restrict__ Wv, const float* __restrict__ Wo,
    const float* __restrict__ W1, const float* __restrict__ W2,
    const float* __restrict__ nw, const float* __restrict__ ppre,
    const float* __restrict__ ppost, const float* __restrict__ pres,
    bf16* __restrict__ wqkv, bf16* __restrict__ wot,
    bf16* __restrict__ w1t, bf16* __restrict__ w2t, bf16* __restrict__ phiw)
{
    const int z = blockIdx.z;
    const int tid = blockIdx.x * 256 + threadIdx.x;
    if (z == 6) {
        if (tid >= 32 * 96) return;          // N=32, K=768, KC=24
        const int n = tid / 96, k8 = tid % 96;
        const int kch = k8 >> 2, quad = k8 & 3;
        const int ntile = n >> 4, nc = n & 15;
        bf16* d = phiw + ((size_t)(ntile * 24 + kch) * 64 + quad * 16 + nc) * 8;
#pragma unroll
        for (int e = 0; e < 8; e++) {
            const int k = k8 * 8 + e;
            float v;
            if      (n < 4)  v = ppre [k * 4  + n];
            else if (n < 8)  v = ppost[k * 4  + n - 4];
            else if (n < 24) v = pres [k * 16 + n - 8];
            else             v = 0.f;
            d[e] = (bf16)(nw[k] * v);
        }
        return;
    }
    const float* src; bf16* dst; int K, N; float scale = 1.f;
    switch (z) {
        case 0: src = Wq; dst = wqkv;            K = 192; N = 192;
                scale = 0.125f * LOG2E; break;   // 1/sqrt(64)*log2e (exp2 softmax)
        case 1: src = Wk; dst = wqkv + 36864;    K = 192; N = 192; break;
        case 2: src = Wv; dst = wqkv + 73728;    K = 192; N = 192; break;
        case 3: src = Wo; dst = wot;             K = 192; N = 192; break;
        case 4: src = W1; dst = w1t;             K = 192; N = 768; break;
        default:src = W2; dst = w2t;             K = 768; N = 192; break;
    }
    const int K8 = K >> 3, KC = K >> 5;
    if (tid >= N * K8) return;
    const int n = tid / K8, k8 = tid % K8;
    const int kch = k8 >> 2, quad = k8 & 3;
    const int ntile = n >> 4, nc = n & 15;
    bf16* d = dst + ((size_t)(ntile * KC + kch) * 64 + quad * 16 + nc) * 8;
#pragma unroll
    for (int e = 0; e < 8; e++)
        d[e] = (bf16)(scale * src[(size_t)(k8 * 8 + e) * N + n]);
}

// ---------------------------------------------------------------------------
// prep: one wave per token. rinv[t] = rsqrt(mean(x^2)+eps); xb = bf16(x)
// ---------------------------------------------------------------------------
__global__ __launch_bounds__(64) void prep_kernel(
    const float* __restrict__ x, bf16* __restrict__ xb, float* __restrict__ rinv)
{
    const int tok = blockIdx.x, lane = threadIdx.x;
    const float* xt = x + (size_t)tok * ND;
    float4 xv[3];
    float ssq = 0.f;
#pragma unroll
    for (int r = 0; r < 3; r++) {
        xv[r] = ((const float4*)xt)[lane + 64 * r];
        ssq += xv[r].x*xv[r].x + xv[r].y*xv[r].y + xv[r].z*xv[r].z + xv[r].w*xv[r].w;
    }
#pragma unroll
    for (int off = 32; off; off >>= 1) ssq += __shfl_xor(ssq, off);
    if (lane == 0) rinv[tok] = rsqrtf(ssq / (float)ND + 1e-8f);
#pragma unroll
    for (int r = 0; r < 3; r++) {
        bf16x4 o = {(bf16)xv[r].x, (bf16)xv[r].y, (bf16)xv[r].z, (bf16)xv[r].w};
        *(bf16x4*)(xb + (size_t)tok * ND + 4 * (lane + 64 * r)) = o;
    }
}

// ---------------------------------------------------------------------------
// dots: MFMA GEMM  dots[t][n] = rinv[t] * (xb[t][:] . phi'[n][:])
// phiw frag-linear (KC=24, 2 n-tiles).
// ---------------------------------------------------------------------------
__global__ __launch_bounds__(256) void dots_kernel(
    const bf16* __restrict__ xb, const bf16* __restrict__ phiw,
    const float* __restrict__ rinv, float* __restrict__ dots)
{
    const int tid = threadIdx.x, lane = tid & 63, w = tid >> 6;
    const int quad = lane >> 4, c = lane & 15;
    const int tok0 = blockIdx.x * 64 + w * 16;

    f32x4 acc0 = {0.f,0.f,0.f,0.f}, acc1 = {0.f,0.f,0.f,0.f};
    const bf16* arow = xb + (size_t)(tok0 + c) * ND + quad * 8;
    const bf16* bbase = phiw + lane * 8;
#pragma unroll 6
    for (int k0 = 0; k0 < ND; k0 += 32) {
        const int kch = k0 >> 5;
        bf16x8 af  = *(const bf16x8*)(arow + k0);
        bf16x8 bf0 = *(const bf16x8*)(bbase + (size_t)kch * 512);
        bf16x8 bf1 = *(const bf16x8*)(bbase + (size_t)(24 + kch) * 512);
        acc0 = MFMA16(af, bf0, acc0);
        acc1 = MFMA16(af, bf1, acc1);
    }
#pragma unroll
    for (int r = 0; r < 4; r++) {
        const int tok = tok0 + quad * 4 + r;
        const float s = rinv[tok];
        dots[(size_t)tok * 32 + c]      = acc0[r] * s;
        dots[(size_t)tok * 32 + 16 + c] = acc1[r] * s;
    }
}

// ---------------------------------------------------------------------------
// sink: ONE LANE PER TOKEN. sigmoid gates + 20-iter 4x4 sinkhorn, all regs.
// hgate[t][20] = {hres[16], hpre[4]}; hpost[t][4].
// ---------------------------------------------------------------------------
__global__ __launch_bounds__(256) void sink_kernel(
    const float* __restrict__ dots, const float* __restrict__ b_pre,
    const float* __restrict__ b_post, const float* __restrict__ b_res,
    const float* __restrict__ a_pre, const float* __restrict__ a_post,
    const float* __restrict__ a_res,
    float* __restrict__ hgate, float* __restrict__ hpost)
{
    const int tok = blockIdx.x * 256 + threadIdx.x;
    const float* dt = dots + (size_t)tok * 32;
    float d[24];
#pragma unroll
    for (int i = 0; i < 6; i++) *(float4*)&d[i*4] = *(const float4*)(dt + i*4);

    const float apre = a_pre[0], apost = a_post[0], ares = a_res[0];
    float hpre[4], hpo[4], m[16];
#pragma unroll
    for (int i = 0; i < 4; i++) {
        hpre[i] = 1.f / (1.f + __expf(-(apre  * d[i]     + b_pre[i])));
        hpo[i]  = 2.f / (1.f + __expf(-(apost * d[4 + i] + b_post[i])));
    }
#pragma unroll
    for (int p = 0; p < 16; p++) m[p] = ares * d[8 + p] + b_res[p];

    float gm = m[0];
#pragma unroll
    for (int p = 1; p < 16; p++) gm = fmaxf(gm, m[p]);
#pragma unroll
    for (int p = 0; p < 16; p++) m[p] = __expf(m[p] - gm);

    for (int it = 0; it < 20; it++) {
#pragma unroll
        for (int i = 0; i < 4; i++) {
            const float inv = 1.f / (m[i*4+0] + m[i*4+1] + m[i*4+2] + m[i*4+3] + 1e-8f);
#pragma unroll
            for (int j = 0; j < 4; j++) m[i*4+j] *= inv;
        }
#pragma unroll
        for (int j = 0; j < 4; j++) {
            const float inv = 1.f / (m[0*4+j] + m[1*4+j] + m[2*4+j] + m[3*4+j] + 1e-8f);
#pragma unroll
            for (int i = 0; i < 4; i++) m[i*4+j] *= inv;
        }
    }

    float* hg = hgate + (size_t)tok * 20;
#pragma unroll
    for (int i = 0; i < 4; i++) *(float4*)(hg + i*4) = *(float4*)&m[i*4];
    *(float4*)(hg + 16) = *(float4*)hpre;
    *(float4*)(hpost + (size_t)tok * 4) = *(float4*)hpo;
}

// ---------------------------------------------------------------------------
// mix: one wave per token. xin = hpre . x streams; h1 = LN1(xin) bf16.
// (x_res is now produced by gemm_w2_final's epilogue.)
// ---------------------------------------------------------------------------
__global__ __launch_bounds__(64) void mix_kernel(
    const bf16* __restrict__ xb, const float* __restrict__ hgate,
    const float* __restrict__ ln1_w, const float* __restrict__ ln1_b,
    float* __restrict__ xin, bf16* __restrict__ h1)
{
    const int tok = blockIdx.x, lane = threadIdx.x;
    __shared__ float ldsx[ND];

    const bf16* xt = xb + (size_t)tok * ND;
#pragma unroll
    for (int r = 0; r < 3; r++) {
        const bf16x4 v = *(const bf16x4*)(xt + 4 * (lane + 64 * r));
        float4 f = {(float)v[0], (float)v[1], (float)v[2], (float)v[3]};
        ((float4*)ldsx)[lane + 64 * r] = f;
    }

    const float* hg = hgate + (size_t)tok * 20 + 16;
    float hpre[4];
#pragma unroll
    for (int i = 0; i < 4; i++) hpre[i] = hg[i];

    __syncthreads();

    float xi[3];
#pragma unroll
    for (int r = 0; r < 3; r++) {
        const int d = lane + 64 * r;
        xi[r] = hpre[0]*ldsx[d] + hpre[1]*ldsx[DIM+d]
              + hpre[2]*ldsx[2*DIM+d] + hpre[3]*ldsx[3*DIM+d];
    }
    float sum = xi[0] + xi[1] + xi[2];
#pragma unroll
    for (int off = 32; off; off >>= 1) sum += __shfl_xor(sum, off);
    const float mean = sum / (float)DIM;
    float vs = (xi[0]-mean)*(xi[0]-mean) + (xi[1]-mean)*(xi[1]-mean) + (xi[2]-mean)*(xi[2]-mean);
#pragma unroll
    for (int off = 32; off; off >>= 1) vs += __shfl_xor(vs, off);
    const float inv = rsqrtf(vs / (float)DIM + 1e-5f);

    float* xint = xin + (size_t)tok * DIM;
    bf16*  ht   = h1  + (size_t)tok * DIM;
#pragma unroll
    for (int r = 0; r < 3; r++) {
        const int d = lane + 64 * r;
        xint[d] = xi[r];
        ht[d]   = (bf16)((xi[r] - mean) * inv * ln1_w[d] + ln1_b[d]);
    }
}

// ---------------------------------------------------------------------------
// Barrier-free bf16 GEMM, frag-linear B. Wave tile 64 tok x 64 n.
// EPI: 0 = bf16 out, 2 = gelu bf16 out
// ---------------------------------------------------------------------------
template<int EPI, int K>
__global__ __launch_bounds__(256) void gemm_bf(
    const bf16* __restrict__ A, const bf16* __restrict__ Bt,
    bf16* __restrict__ Cb, int N)
{
    const int tid = threadIdx.x, lane = tid & 63, w = tid >> 6;
    const int quad = lane >> 4, c = lane & 15;
    const int tok0 = blockIdx.y * 256 + w * 64;
    const int n0   = blockIdx.x * 64;
    const int KC   = K >> 5;

    f32x4 acc[4][4];
#pragma unroll
    for (int i = 0; i < 4; i++)
#pragma unroll
        for (int j = 0; j < 4; j++) acc[i][j] = (f32x4){0.f,0.f,0.f,0.f};

    const bf16* abase = A + (size_t)(tok0 + c) * K + quad * 8;
    const bf16* bbase = Bt + (size_t)(n0 >> 4) * KC * 512 + lane * 8;
#pragma unroll 2
    for (int k0 = 0; k0 < K; k0 += 32) {
        const int kch = k0 >> 5;
        bf16x8 af[4], bfr[4];
#pragma unroll
        for (int mt = 0; mt < 4; mt++)
            af[mt] = *(const bf16x8*)(abase + (size_t)mt * 16 * K + k0);
#pragma unroll
        for (int nt = 0; nt < 4; nt++)
            bfr[nt] = *(const bf16x8*)(bbase + (size_t)(nt * KC + kch) * 512);
#pragma unroll
        for (int mt = 0; mt < 4; mt++)
#pragma unroll
            for (int nt = 0; nt < 4; nt++)
                acc[mt][nt] = MFMA16(af[mt], bfr[nt], acc[mt][nt]);
    }

#pragma unroll
    for (int mt = 0; mt < 4; mt++)
#pragma unroll
        for (int r = 0; r < 4; r++) {
            const int row = tok0 + mt*16 + quad*4 + r;
#pragma unroll
            for (int nt = 0; nt < 4; nt++) {
                float v = acc[mt][nt][r];
                if (EPI == 2) v = gelu_tanh(v);
                Cb[(size_t)row * N + n0 + nt*16 + c] = (bf16)v;
            }
        }
}

// ---------------------------------------------------------------------------
// Wo GEMM + residual + LN2 fused. Wave = 16 tokens x 192 cols (nt=12).
// x1 = xin + obuf@Wo (fp32);  h2 = LN2(x1) (bf16). Frag-linear B, KC=6.
// ---------------------------------------------------------------------------
__global__ __launch_bounds__(256) void gemm_wo_ln(
    const bf16* __restrict__ A, const bf16* __restrict__ Bt,
    const float* __restrict__ xin, const float* __restrict__ lw,
    const float* __restrict__ lb, float* __restrict__ x1, bf16* __restrict__ h2)
{
    const int tid = threadIdx.x, lane = tid & 63, w = tid >> 6;
    const int quad = lane >> 4, c = lane & 15;
    const int tok0 = blockIdx.x * 64 + w * 16;

    f32x4 acc[12];
#pragma unroll
    for (int j = 0; j < 12; j++) acc[j] = (f32x4){0.f,0.f,0.f,0.f};

    const bf16* abase = A + (size_t)(tok0 + c) * 192 + quad * 8;
    const bf16* bbase = Bt + lane * 8;
#pragma unroll 2
    for (int k0 = 0; k0 < 192; k0 += 32) {
        const int kch = k0 >> 5;
        bf16x8 af = *(const bf16x8*)(abase + k0);
#pragma unroll
        for (int nt = 0; nt < 12; nt++) {
            bf16x8 bfr = *(const bf16x8*)(bbase + (size_t)(nt * 6 + kch) * 512);
            acc[nt] = MFMA16(af, bfr, acc[nt]);
        }
    }

#pragma unroll
    for (int r = 0; r < 4; r++) {
        const int row = tok0 + quad*4 + r;
        float v[12], s = 0.f;
#pragma unroll
        for (int nt = 0; nt < 12; nt++) {
            v[nt] = acc[nt][r] + xin[(size_t)row * 192 + nt*16 + c];
            s += v[nt];
        }
#pragma unroll
        for (int off = 1; off < 16; off <<= 1) s += __shfl_xor(s, off);
        const float mean = s / 192.f;
        float vv = 0.f;
#pragma unroll
        for (int nt = 0; nt < 12; nt++) {
            const float d = v[nt] - mean;
            vv += d * d;
        }
#pragma unroll
        for (int off = 1; off < 16; off <<= 1) vv += __shfl_xor(vv, off);
        const float inv = rsqrtf(vv / 192.f + 1e-5f);
#pragma unroll
        for (int nt = 0; nt < 12; nt++) {
            const int col = nt*16 + c;
            x1[(size_t)row * 192 + col] = v[nt];
            h2[(size_t)row * 192 + col] = (bf16)((v[nt] - mean) * inv * lw[col] + lb[col]);
        }
    }
}

// ---------------------------------------------------------------------------
// W2 GEMM + residual + h_post scale + x_res, fully fused; out is WRITE-ONLY.
// v3: gemm_bf's proven 64-tok x 64-col wave tile (mt=4): FOUR independent
// A-loads feed 16 MFMAs per K-step -> 4-deep natural load pipelining.
// Grid (3, TOKENS/256); A re-read 3x (cheap: L3-resident).
// out[t][i][col] = sum_j hres[i][j]*x[t][j][col] + (x1+g@W2)[t][col]*hpost[t][i]
// ---------------------------------------------------------------------------
__global__ __launch_bounds__(256) void gemm_w2_final(
    const bf16* __restrict__ A, const bf16* __restrict__ Bt,
    const float* __restrict__ x1, const float* __restrict__ x,
    const float* __restrict__ hgate, const float* __restrict__ hpost,
    float* __restrict__ out)
{
    const int tid = threadIdx.x, lane = tid & 63, w = tid >> 6;
    const int quad = lane >> 4, c = lane & 15;
    const int tok0 = blockIdx.y * 256 + w * 64;
    const int n0   = blockIdx.x * 64;

    f32x4 acc[4][4];
#pragma unroll
    for (int i = 0; i < 4; i++)
#pragma unroll
        for (int j = 0; j < 4; j++) acc[i][j] = (f32x4){0.f,0.f,0.f,0.f};

    const bf16* abase = A + (size_t)(tok0 + c) * 768 + quad * 8;
    const bf16* bbase = Bt + (size_t)(n0 >> 4) * 24 * 512 + lane * 8;
#pragma unroll 2
    for (int k0 = 0; k0 < 768; k0 += 32) {
        const int kch = k0 >> 5;
        bf16x8 af[4], bfr[4];
#pragma unroll
        for (int mt = 0; mt < 4; mt++)
            af[mt] = *(const bf16x8*)(abase + (size_t)mt * 16 * 768 + k0);
#pragma unroll
        for (int nt = 0; nt < 4; nt++)
            bfr[nt] = *(const bf16x8*)(bbase + (size_t)(nt * 24 + kch) * 512);
#pragma unroll
        for (int mt = 0; mt < 4; mt++)
#pragma unroll
            for (int nt = 0; nt < 4; nt++)
                acc[mt][nt] = MFMA16(af[mt], bfr[nt], acc[mt][nt]);
    }

#pragma unroll
    for (int mt = 0; mt < 4; mt++)
#pragma unroll
        for (int r = 0; r < 4; r++) {
            const int row = tok0 + mt*16 + quad*4 + r;
            const float* hg = hgate + (size_t)row * 20;
            float hres[16];
#pragma unroll
            for (int p = 0; p < 16; p++) hres[p] = hg[p];
            const float4 hp = *(const float4*)(hpost + (size_t)row * 4);
            const float hpi[4] = {hp.x, hp.y, hp.z, hp.w};
            const float* xrow = x + (size_t)row * ND;
            float* orow = out + (size_t)row * ND;
#pragma unroll
            for (int nt = 0; nt < 4; nt++) {
                const int col = n0 + nt*16 + c;
                const float y = acc[mt][nt][r] + x1[(size_t)row * 192 + col];
                float xv[4];
#pragma unroll
                for (int j = 0; j < 4; j++) xv[j] = xrow[j * 192 + col];
#pragma unroll
                for (int i = 0; i < 4; i++) {
                    const float xr = hres[i*4+0]*xv[0] + hres[i*4+1]*xv[1]
                                   + hres[i*4+2]*xv[2] + hres[i*4+3]*xv[3];
                    orow[i * 192 + col] = xr + y * hpi[i];
                }
            }
        }
}

// ---------------------------------------------------------------------------
// V transpose: qkv[tok][384+h*64+d] -> vt[bh][d][seq]  (bf16)
// ---------------------------------------------------------------------------
__global__ __launch_bounds__(256) void vtrans_kernel(
    const bf16* __restrict__ qkv, bf16* __restrict__ vt)
{
    __shared__ bf16 t[64][72];
    const int tid = threadIdx.x;
    const int bh = blockIdx.y, b = bh / NH, h = bh % NH;
    const int s0 = blockIdx.x * 64;

#pragma unroll
    for (int i = 0; i < 2; i++) {
        const int chunk = tid + 256 * i;
        const int srow = chunk >> 3, g = chunk & 7;
        *(uint4*)&t[srow][g * 8] =
            *(const uint4*)(qkv + (size_t)(b * SEQ + s0 + srow) * 576 + 384 + h * 64 + g * 8);
    }
    __syncthreads();
#pragma unroll
    for (int i = 0; i < 2; i++) {
        const int chunk = tid + 256 * i;
        const int d = chunk >> 3, sg = chunk & 7;
        bf16x8 v;
#pragma unroll
        for (int j = 0; j < 8; j++) v[j] = t[sg * 8 + j][d];
        *(bf16x8*)(vt + ((size_t)bh * HD + d) * SEQ + s0 + sg * 8) = v;
    }
}

// ---------------------------------------------------------------------------
// attn helpers (deferred-PV pipeline, all static indexing)
// ---------------------------------------------------------------------------
__device__ __forceinline__ void attn_load_v(
    int kt, const bf16* __restrict__ vbase, int quad, int c, bf16x8 (&vf)[2][4])
{
#pragma unroll
    for (int ch = 0; ch < 2; ch++)
#pragma unroll
        for (int dt = 0; dt < 4; dt++)
            vf[ch][dt] = *(const bf16x8*)(vbase + (size_t)(dt*16 + c) * SEQ
                                          + kt*64 + ch*32 + quad*8);
}

__device__ __forceinline__ void attn_load_pf(
    const bf16* __restrict__ PwPrev, int quad, int c, bf16x8 (&pf)[2][2])
{
#pragma unroll
    for (int ch = 0; ch < 2; ch++)
#pragma unroll
        for (int mt = 0; mt < 2; mt++)
            pf[ch][mt] = *(const bf16x8*)(PwPrev + (mt*16 + c)*64
                                          + (((ch*4 + quad) ^ (c & 7)) * 8));
}

// QK(kt): prefetch K(kt+1) into knxt, 8 QK MFMAs from kcur, exp2, lst accum,
// swizzled Pw store. No PV here (deferred to next iteration).
__device__ __forceinline__ void attn_qk_phase(
    int kt, bool pref,
    const bf16* __restrict__ kbase,
    bf16* __restrict__ PwCur, int quad, int c,
    const bf16x8 (&qf)[2][2],
    const bf16x8 (&kcur)[2][4], bf16x8 (&knxt)[2][4],
    float (&lst)[2][4])
{
    if (pref) {
#pragma unroll
        for (int ch = 0; ch < 2; ch++)
#pragma unroll
            for (int nt = 0; nt < 4; nt++)
                knxt[ch][nt] = *(const bf16x8*)(kbase
                    + (size_t)((kt+1)*64 + nt*16 + c) * 576 + ch*32 + quad*8);
    }

    f32x4 sf[2][4];
#pragma unroll
    for (int mt = 0; mt < 2; mt++)
#pragma unroll
        for (int nt = 0; nt < 4; nt++) sf[mt][nt] = (f32x4){0.f, 0.f, 0.f, 0.f};
#pragma unroll
    for (int ch = 0; ch < 2; ch++)
#pragma unroll
        for (int mt = 0; mt < 2; mt++)
#pragma unroll
            for (int nt = 0; nt < 4; nt++)
                sf[mt][nt] = MFMA16(qf[mt][ch], kcur[ch][nt], sf[mt][nt]);

#pragma unroll
    for (int mt = 0; mt < 2; mt++)
#pragma unroll
        for (int r = 0; r < 4; r++) {
            float rs = 0.f;
#pragma unroll
            for (int nt = 0; nt < 4; nt++) {
                const float p = EXP2F(sf[mt][nt][r]);
                sf[mt][nt][r] = p;
                rs += p;
            }
            lst[mt][r] += rs;
        }

#pragma unroll
    for (int mt = 0; mt < 2; mt++)
#pragma unroll
        for (int nt = 0; nt < 4; nt++)
#pragma unroll
            for (int r = 0; r < 4; r++) {
                const int row = mt*16 + quad*4 + r;
                const int col = nt*16 + c;
                PwCur[row*64 + (((col >> 3) ^ (row & 7)) * 8) + (col & 7)] =
                    (bf16)sf[mt][nt][r];
            }
}

__device__ __forceinline__ void attn_pv_accum(
    const bf16x8 (&pf)[2][2], const bf16x8 (&vf)[2][4], f32x4 (&of)[2][4])
{
#pragma unroll
    for (int ch = 0; ch < 2; ch++)
#pragma unroll
        for (int mt = 0; mt < 2; mt++)
#pragma unroll
            for (int dt = 0; dt < 4; dt++)
                of[mt][dt] = MFMA16(pf[ch][mt], vf[ch][dt], of[mt][dt]);
}

// ---------------------------------------------------------------------------
// MFMA flash attention v6 (REVERT to R9's measured-best config, 523.45us
// total / attn 100.3us @ 156 VGPR, zero spill). R10's launch_bounds(64,4)
// floor made the allocator emit 64 VGPR -> massive scratch spills (FETCH
// 538MB, WRITE 649MB, attn 265us). Occupancy floors via launch_bounds are a
// dead lever on this toolchain for these bodies (R2, R10) -- do not re-add.
// Deferred-PV pipeline: iteration t issues V(t-1) loads + Pw[prev] reads,
// then QK(t) [K(t+1) prefetch, MFMA, exp2, Pw[cur] store], then PV(t-1).
// Pw double-buffered (2x4KB LDS), static parity via unroll-2 named buffers.
// Single wave per block, grid (32,96) (same-bh blocks warm L2 per XCD).
// exp2 softmax (log2e/8 folded into Wq), row-sum deferred to epilogue.
// ---------------------------------------------------------------------------
__global__ __launch_bounds__(64) void attn_mfma(
    const bf16* __restrict__ qkv, const bf16* __restrict__ vt,
    bf16* __restrict__ obuf)
{
    __shared__ bf16 PwBuf[2][32 * 64];
    const int lane = threadIdx.x;
    const int quad = lane >> 4, c = lane & 15;
    const int bh = blockIdx.y, b = bh / NH, h = bh % NH;
    const int q0 = blockIdx.x * 32;

    bf16* Pw0 = PwBuf[0];
    bf16* Pw1 = PwBuf[1];

    const bf16* kbase = qkv + (size_t)b * SEQ * 576 + 192 + h * 64;
    const bf16* vbase = vt + (size_t)bh * HD * SEQ;

    bf16x8 qf[2][2];
#pragma unroll
    for (int mt = 0; mt < 2; mt++)
#pragma unroll
        for (int ch = 0; ch < 2; ch++)
            qf[mt][ch] = *(const bf16x8*)(qkv + (size_t)(b * SEQ + q0 + mt*16 + c) * 576
                                              + h * 64 + ch * 32 + quad * 8);

    f32x4 of[2][4];
    float lst[2][4];
#pragma unroll
    for (int mt = 0; mt < 2; mt++)
#pragma unroll
        for (int r = 0; r < 4; r++) lst[mt][r] = 0.f;
#pragma unroll
    for (int mt = 0; mt < 2; mt++)
#pragma unroll
        for (int dt = 0; dt < 4; dt++) of[mt][dt] = (f32x4){0.f, 0.f, 0.f, 0.f};

    // preload K(0) into kfA, run QK(0) -> Pw0 (even tiles use kfA/Pw0)
    bf16x8 kfA[2][4], kfB[2][4];
#pragma unroll
    for (int ch = 0; ch < 2; ch++)
#pragma unroll
        for (int nt = 0; nt < 4; nt++)
            kfA[ch][nt] = *(const bf16x8*)(kbase + (size_t)(nt*16 + c) * 576
                                           + ch * 32 + quad * 8);
    attn_qk_phase(0, true, kbase, Pw0, quad, c, qf, kfA, kfB, lst);

    // steady state: t = 1..14 (7 double-iterations)
#pragma unroll 1
    for (int t = 1; t <= 13; t += 2) {
        {   // odd t: QK uses kfB -> Pw1; PV(t-1) from Pw0
            bf16x8 vf[2][4], pf[2][2];
            attn_load_v(t - 1, vbase, quad, c, vf);
            attn_load_pf(Pw0, quad, c, pf);
            attn_qk_phase(t, true, kbase, Pw1, quad, c, qf, kfB, kfA, lst);
            attn_pv_accum(pf, vf, of);
        }
        {   // even t+1: QK uses kfA -> Pw0; PV(t) from Pw1
            bf16x8 vf[2][4], pf[2][2];
            attn_load_v(t, vbase, quad, c, vf);
            attn_load_pf(Pw1, quad, c, pf);
            attn_qk_phase(t + 1, true, kbase, Pw0, quad, c, qf, kfA, kfB, lst);
            attn_pv_accum(pf, vf, of);
        }
    }
    {   // t = 15 (odd): QK uses kfB -> Pw1 (no more prefetch); PV(14) from Pw0
        bf16x8 vf[2][4], pf[2][2];
        attn_load_v(14, vbase, quad, c, vf);
        attn_load_pf(Pw0, quad, c, pf);
        attn_qk_phase(15, false, kbase, Pw1, quad, c, qf, kfB, kfA, lst);
        attn_pv_accum(pf, vf, of);
    }
    {   // drain: PV(15) from Pw1
        bf16x8 vf[2][4], pf[2][2];
        attn_load_v(15, vbase, quad, c, vf);
        attn_load_pf(Pw1, quad, c, pf);
        attn_pv_accum(pf, vf, of);
    }

#pragma unroll
    for (int mt = 0; mt < 2; mt++)
#pragma unroll
        for (int r = 0; r < 4; r++) {
            float s = lst[mt][r];
#pragma unroll
            for (int off = 1; off < 16; off <<= 1) s += __shfl_xor(s, off);
            const float inv = 1.0f / s;
            const size_t tok = (size_t)b * SEQ + q0 + mt*16 + quad*4 + r;
#pragma unroll
            for (int dt = 0; dt < 4; dt++)
                obuf[tok * DIM + h*64 + dt*16 + c] = (bf16)(of[mt][dt][r] * inv);
        }
}

// ---------------------------------------------------------------------------
extern "C" void kernel_launch(void* const* d_in, const int* in_sizes, int n_in,
                              void* d_out, int out_size, void* d_ws, size_t ws_size,
                              hipStream_t stream) {
    const float* x         = (const float*)d_in[0];
    const float* norm_w    = (const float*)d_in[1];
    const float* phi_pre   = (const float*)d_in[2];
    const float* phi_post  = (const float*)d_in[3];
    const float* phi_res   = (const float*)d_in[4];
    const float* b_pre     = (const float*)d_in[5];
    const float* b_post    = (const float*)d_in[6];
    const float* b_res     = (const float*)d_in[7];
    const float* alpha_pre = (const float*)d_in[8];
    const float* alpha_post= (const float*)d_in[9];
    const float* alpha_res = (const float*)d_in[10];
    const float* ln1_w     = (const float*)d_in[11];
    const float* ln1_b     = (const float*)d_in[12];
    const float* Wq        = (const float*)d_in[13];
    const float* Wk        = (const float*)d_in[14];
    const float* Wv        = (const float*)d_in[15];
    const float* Wo        = (const float*)d_in[16];
    const float* ln2_w     = (const float*)d_in[17];
    const float* ln2_b     = (const float*)d_in[18];
    const float* W1        = (const float*)d_in[19];
    const float* W2        = (const float*)d_in[20];

    float* out = (float*)d_out;
    float* ws  = (float*)d_ws;

    // ---- workspace carve (float units) — total ~130 MB ----
    const size_t TBf = (size_t)TOKENS * DIM;         // 6,291,456
    float* xin   = ws;                                // fp32 [TBf]
    float* x1    = ws + TBf;                          // fp32 [TBf]
    float* hpost = ws + 2 * TBf;                      // fp32 [131072]
    float* rinv  = hpost + 131072;                    // fp32 [32768]
    float* hgate = rinv + 32768;                      // fp32 [TOKENS*20] (alive to end!)
    bf16*  phiw  = (bf16*)(hgate + (size_t)TOKENS*20);// frag-linear [24576]
    bf16*  wqkv  = phiw + 24576;                      // [110592]
    bf16*  wot   = wqkv + 110592;                     // [36864]
    bf16*  w1t   = wot + 36864;                       // [147456]
    bf16*  w2t   = w1t + 147456;                      // [147456]
    float* regAC = (float*)(w2t + 147456);            // 12,582,912 floats
    bf16*  xb    = (bf16*)regAC;                      // [32768][768] (dead after mix)
    bf16*  qkv   = (bf16*)regAC;                      // [32768][576]
    bf16*  vt    = qkv + (size_t)TOKENS * 576;        // [96][64][1024]
    bf16*  gbuf  = (bf16*)regAC;                      // [32768][768] (after attn)
    float* regBD = regAC + 12582912;
    bf16*  h1    = (bf16*)regBD;                      // [32768][192]
    bf16*  obuf  = h1;                                // alias (h1 dead after QKV)
    bf16*  h2    = h1 + TBf;                          // [32768][192]
    float* dotsb = regBD + TBf / 2;                   // aliases h2 slot (dead before wo_ln)

    // 0. weight prep (frag-linear; 1/sqrt(64)*log2e folded into Wq)
    wprep_kernel<<<dim3(72, 1, 7), 256, 0, stream>>>(
        Wq, Wk, Wv, Wo, W1, W2, norm_w, phi_pre, phi_post, phi_res,
        wqkv, wot, w1t, w2t, phiw);

    // 1. gating pipeline
    prep_kernel<<<TOKENS, 64, 0, stream>>>(x, xb, rinv);
    dots_kernel<<<TOKENS / 64, 256, 0, stream>>>(xb, phiw, rinv, dotsb);
    sink_kernel<<<TOKENS / 256, 256, 0, stream>>>(
        dotsb, b_pre, b_post, b_res, alpha_pre, alpha_post, alpha_res, hgate, hpost);
    mix_kernel<<<TOKENS, 64, 0, stream>>>(xb, hgate, ln1_w, ln1_b, xin, h1);

    // 2. fused QKV projection (barrier-free, frag-linear B)
    gemm_bf<0, 192><<<dim3(576/64, TOKENS/256), 256, 0, stream>>>(h1, wqkv, qkv, 576);

    // 3. V transpose
    vtrans_kernel<<<dim3(SEQ/64, BATCH*NH), 256, 0, stream>>>(qkv, vt);

    // 4. attention -> obuf bf16 (1-wave blocks, deferred-PV pipeline)
    attn_mfma<<<dim3(SEQ/32, BATCH*NH), 64, 0, stream>>>(qkv, vt, obuf);

    // 5. x1 = xin + obuf @ Wo, h2 = LN2(x1)  (fused)
    gemm_wo_ln<<<TOKENS/64, 256, 0, stream>>>(obuf, wot, xin, ln2_w, ln2_b, x1, h2);

    // 6. g = gelu(h2 @ W1) bf16 (barrier-free, fast-gelu epilogue)
    gemm_bf<2, 192><<<dim3(768/64, TOKENS/256), 256, 0, stream>>>(h2, w1t, gbuf, 768);

    // 7. out = x_res + (x1 + g @ W2) * h_post  (fused; 64x64 wave tile, mt=4)
    gemm_w2_final<<<dim3(3, TOKENS/256), 256, 0, stream>>>(
        gbuf, w2t, x1, x, hgate, hpost, out);
}